// Round 8
// baseline (107.901 us; speedup 1.0000x reference)
//
#include <hip/hip_runtime.h>
#include <math.h>

#define TOKENS 16384
#define HID    2048
#define TAU    0.02f
#define NCH    8            // K-chunks of 256 fp32

typedef float f4 __attribute__((ext_vector_type(4)));
typedef short s8v __attribute__((ext_vector_type(8)));

// ws byte layout
#define WS_W1    0                      // ushort[64*2048] bf16 weights (256KB)
#define WS_SLIST 262144                 // uint2[16384] suspect list (128KB)
#define WS_BP    393216                 // float[1024*128] (512KB)
#define WS_G2    917504                 // float[64*128] (32KB)
#define WS_CNTF  950272                 // float[64]
#define WS_SCNT  950528                 // unsigned[1]

__device__ __forceinline__ unsigned short bf16rne(float x) {
  unsigned u = __float_as_uint(x);
  return (unsigned short)((u + 0x7FFFu + ((u >> 16) & 1u)) >> 16);
}

__device__ __forceinline__ void gl16(const void* g, const void* l) {
  __builtin_amdgcn_global_load_lds(
      (const __attribute__((address_space(1))) void*)g,
      (__attribute__((address_space(3))) void*)l, 16, 0, 0);
}

// fp32 weights -> bf16 (RNE); also zeroes fixup counters
__global__ __launch_bounds__(256) void k_pack(const float* __restrict__ gw,
                                              unsigned short* __restrict__ w1,
                                              float* __restrict__ cntf,
                                              unsigned* __restrict__ scnt) {
  if (blockIdx.x == 0) {
    if (threadIdx.x < 64) cntf[threadIdx.x] = 0.f;
    if (threadIdx.x == 64) *scnt = 0u;
  }
  int gid = blockIdx.x * 256 + threadIdx.x;
  int m = gid * 8;
  f4 a = *(const f4*)(gw + m);
  f4 b = *(const f4*)(gw + m + 4);
  unsigned short r[8] = {bf16rne(a.x), bf16rne(a.y), bf16rne(a.z), bf16rne(a.w),
                         bf16rne(b.x), bf16rne(b.y), bf16rne(b.z), bf16rne(b.w)};
  *(s8v*)(w1 + m) = *(s8v*)r;
}

__global__ __launch_bounds__(256, 4) void k_main(const float* __restrict__ hid,
                                                 const unsigned short* __restrict__ w1,
                                                 float* __restrict__ out,
                                                 float* __restrict__ bp,
                                                 uint2* __restrict__ slist,
                                                 unsigned* __restrict__ scnt) {
  // LDS: 2 bufs x 16KB; buf = A fp32 [16 tok][256 k], 16B granules XOR-swizzled in-row
  __shared__ __align__(16) char lds[32768];
  const int tid = threadIdx.x, wave = tid >> 6, lane = tid & 63;
  const int l15 = lane & 15, ks = lane >> 4;
  const int tok0 = blockIdx.x * 16;
  const int phase = blockIdx.x & 7;          // diagonal K-phase (channel de-camping)
  const char* hb = (const char*)hid;

  size_t asrc[4];
  int adst[4];
  #pragma unroll
  for (int j = 0; j < 4; ++j) {
    int row = j * 4 + wave;
    asrc[j] = (size_t)(tok0 + row) * 8192 + (size_t)((lane ^ (row & 7)) << 4);
    adst[j] = j * 4096 + wave * 1024;
  }

  f4 acc = {0.f, 0.f, 0.f, 0.f};
  const int sw = l15 & 7;
  const char* w1b = (const char*)w1;
  const size_t brow = (size_t)(wave * 16 + l15) * 4096 + ks * 16;

  auto issueA = [&](int c, int bufb) {
    const int pc = (c + phase) & 7;
    #pragma unroll
    for (int j = 0; j < 4; ++j)
      gl16(hb + asrc[j] + (size_t)pc * 1024, lds + bufb + adst[j]);
  };
  auto compute = [&](int c, int bufb) {
    const int pc = (c + phase) & 7;
    #pragma unroll
    for (int s = 0; s < 8; ++s) {
      f4 a0 = *(const f4*)(lds + bufb + l15 * 1024 + (((s * 8 + ks * 2) ^ sw) << 4));
      f4 a1 = *(const f4*)(lds + bufb + l15 * 1024 + (((s * 8 + ks * 2 + 1) ^ sw) << 4));
      unsigned short af8[8] = {bf16rne(a0.x), bf16rne(a0.y), bf16rne(a0.z), bf16rne(a0.w),
                               bf16rne(a1.x), bf16rne(a1.y), bf16rne(a1.z), bf16rne(a1.w)};
      s8v af = *(s8v*)af8;
      s8v bf = *(const s8v*)(w1b + brow + (size_t)pc * 512 + s * 64);
      acc = __builtin_amdgcn_mfma_f32_16x16x32_bf16(af, bf, acc, 0, 0, 0);
    }
  };

  issueA(0, 0);
  __syncthreads();
  for (int c = 0; c < NCH; ++c) {
    if (c + 1 < NCH) issueA(c + 1, ((c + 1) & 1) * 16384);
    compute(c, (c & 1) * 16384);
    __syncthreads();
  }

  // park logits [16 tok][68]: row = ks*4+r (token), col = wave*16 + l15 (expert)
  float* lf = (float*)lds;
  #pragma unroll
  for (int r = 0; r < 4; ++r)
    lf[(ks * 4 + r) * 68 + wave * 16 + l15] = acc[r];
  __syncthreads();

  float spacc = 0.f, cntacc = 0.f;
  for (int it = 0; it < 4; ++it) {
    const int tl = wave * 4 + it;
    float lg = lf[tl * 68 + lane];
    float m1 = lg;
    #pragma unroll
    for (int d = 1; d < 64; d <<= 1) m1 = fmaxf(m1, __shfl_xor(m1, d));
    int c0 = (lg == m1) ? lane : 64;
    #pragma unroll
    for (int d = 1; d < 64; d <<= 1) c0 = min(c0, __shfl_xor(c0, d));
    float lx1 = (lane == c0) ? -INFINITY : lg;
    float m2 = lx1;
    #pragma unroll
    for (int d = 1; d < 64; d <<= 1) m2 = fmaxf(m2, __shfl_xor(m2, d));
    int c1 = (lx1 == m2) ? lane : 64;
    #pragma unroll
    for (int d = 1; d < 64; d <<= 1) c1 = min(c1, __shfl_xor(c1, d));
    float lx2 = (lane == c0 || lane == c1) ? -INFINITY : lg;
    float m3 = lx2;
    #pragma unroll
    for (int d = 1; d < 64; d <<= 1) m3 = fmaxf(m3, __shfl_xor(m3, d));

    float p = __expf(lg - m1);
    float Z = p;
    #pragma unroll
    for (int d = 1; d < 64; d <<= 1) Z += __shfl_xor(Z, d);
    spacc = fmaf(p, 1.f / Z, spacc);

    const bool suspect = (m1 - m2 < TAU) || (m2 - m3 < TAU);
    if (!suspect) cntacc += ((lane == c0) ? 1.f : 0.f) + ((lane == c1) ? 1.f : 0.f);

    float gr = __expf(m2 - m1);
    float r0 = 1.f / (1.f + gr);
    if (lane == 0) {
      int t = tok0 + tl;
      out[(size_t)t * 2]     = r0;
      out[(size_t)t * 2 + 1] = gr * r0;
      out[(size_t)TOKENS * 2 + t * 2]     = (float)c0;
      out[(size_t)TOKENS * 2 + t * 2 + 1] = (float)c1;
    }
    if (suspect) {
      int c2 = (lx2 == m3) ? lane : 64;
      #pragma unroll
      for (int d = 1; d < 64; d <<= 1) c2 = min(c2, __shfl_xor(c2, d));
      float lx3 = (lane == c0 || lane == c1 || lane == c2) ? -INFINITY : lg;
      float m4 = lx3;
      #pragma unroll
      for (int d = 1; d < 64; d <<= 1) m4 = fmaxf(m4, __shfl_xor(m4, d));
      int c3 = (lx3 == m4) ? lane : 64;
      #pragma unroll
      for (int d = 1; d < 64; d <<= 1) c3 = min(c3, __shfl_xor(c3, d));
      if (lane == 0) {
        unsigned idx = atomicAdd(scnt, 1u);
        slist[idx] = make_uint2((unsigned)(tok0 + tl),
            (unsigned)c0 | ((unsigned)c1 << 8) | ((unsigned)c2 << 16) | ((unsigned)c3 << 24));
      }
    }
  }

  float* red = lf + 1088;
  red[wave * 128 + lane]      = spacc;
  red[wave * 128 + 64 + lane] = cntacc;
  __syncthreads();
  if (tid < 128) {
    float s = red[tid] + red[128 + tid] + red[256 + tid] + red[384 + tid];
    bp[(size_t)blockIdx.x * 128 + tid] = s;
  }
}

// exact fp32 re-rank of bf16 top-4 for suspect tokens
__global__ __launch_bounds__(256) void k_fixup(const float* __restrict__ hid,
                                               const float* __restrict__ gw,
                                               float* __restrict__ out,
                                               float* __restrict__ cntf,
                                               const uint2* __restrict__ slist,
                                               const unsigned* __restrict__ scnt) {
  const int lane = threadIdx.x & 63;
  const int wgid = blockIdx.x * 4 + (threadIdx.x >> 6);
  const unsigned S = *scnt;
  for (unsigned j = wgid; j < S; j += 1024) {
    uint2 rec = slist[j];
    const int tok = (int)rec.x;
    const float* hrow = hid + (size_t)tok * HID;
    f4 h[8];
    #pragma unroll
    for (int i = 0; i < 8; ++i) h[i] = *(const f4*)(hrow + lane * 4 + i * 256);
    float lgv[4]; int ide[4];
    #pragma unroll
    for (int c4 = 0; c4 < 4; ++c4) {
      int e = (int)((rec.y >> (8 * c4)) & 255u);
      const float* wr = gw + (size_t)e * HID;
      float s = 0.f;
      #pragma unroll
      for (int i = 0; i < 8; ++i) {
        f4 w = *(const f4*)(wr + lane * 4 + i * 256);
        s = fmaf(h[i].x, w.x, s); s = fmaf(h[i].y, w.y, s);
        s = fmaf(h[i].z, w.z, s); s = fmaf(h[i].w, w.w, s);
      }
      #pragma unroll
      for (int d = 1; d < 64; d <<= 1) s += __shfl_xor(s, d);
      lgv[c4] = s; ide[c4] = e;
    }
    #define SW(a,b) { bool sup = (lgv[b] > lgv[a]) || (lgv[b] == lgv[a] && ide[b] < ide[a]); \
      if (sup) { float tf = lgv[a]; lgv[a] = lgv[b]; lgv[b] = tf; \
                 int ti = ide[a]; ide[a] = ide[b]; ide[b] = ti; } }
    SW(0,1); SW(2,3); SW(0,2); SW(1,3); SW(1,2);
    #undef SW
    float gr = __expf(lgv[1] - lgv[0]);
    float r0 = 1.f / (1.f + gr);
    if (lane == 0) {
      out[(size_t)tok * 2]     = r0;
      out[(size_t)tok * 2 + 1] = gr * r0;
      out[(size_t)TOKENS * 2 + tok * 2]     = (float)ide[0];
      out[(size_t)TOKENS * 2 + tok * 2 + 1] = (float)ide[1];
      atomicAdd(&cntf[ide[0]], 1.f);
      atomicAdd(&cntf[ide[1]], 1.f);
    }
  }
}

__global__ __launch_bounds__(128) void k_loss1(const float* __restrict__ bp,
                                               float* __restrict__ g2) {
  float s = 0.f;
  #pragma unroll 4
  for (int j = 0; j < 16; ++j)
    s += bp[(size_t)(blockIdx.x * 16 + j) * 128 + threadIdx.x];
  g2[(size_t)blockIdx.x * 128 + threadIdx.x] = s;
}

__global__ __launch_bounds__(128) void k_loss2(const float* __restrict__ g2,
                                               const float* __restrict__ cntf,
                                               float* __restrict__ out) {
  const int tid = threadIdx.x;
  float s = 0.f;
  #pragma unroll 8
  for (int j = 0; j < 64; ++j) s += g2[(size_t)j * 128 + tid];
  __shared__ float red[128];
  red[tid] = s;
  __syncthreads();
  if (tid < 64) {
    float v = red[tid] * (red[64 + tid] + cntf[tid]);
    #pragma unroll
    for (int d = 1; d < 64; d <<= 1) v += __shfl_xor(v, d);
    if (tid == 0)
      out[(size_t)TOKENS * 4] = 0.01f * 64.f * v / (16384.f * 16384.f);
  }
}

extern "C" void kernel_launch(void* const* d_in, const int* in_sizes, int n_in,
                              void* d_out, int out_size, void* d_ws, size_t ws_size,
                              hipStream_t stream) {
  (void)in_sizes; (void)n_in; (void)out_size; (void)ws_size;
  const float* hid = (const float*)d_in[0];
  const float* gw  = (const float*)d_in[1];
  float* out = (float*)d_out;
  char* ws = (char*)d_ws;
  unsigned short* w1 = (unsigned short*)(ws + WS_W1);
  uint2* slist = (uint2*)(ws + WS_SLIST);
  float* bp    = (float*)(ws + WS_BP);
  float* g2    = (float*)(ws + WS_G2);
  float* cntf  = (float*)(ws + WS_CNTF);
  unsigned* scnt = (unsigned*)(ws + WS_SCNT);

  k_pack <<<64, 256, 0, stream>>>(gw, w1, cntf, scnt);
  k_main <<<1024, 256, 0, stream>>>(hid, w1, out, bp, slist, scnt);
  k_fixup<<<256, 256, 0, stream>>>(hid, gw, out, cntf, slist, scnt);
  k_loss1<<<64, 128, 0, stream>>>(bp, g2);
  k_loss2<<<1, 128, 0, stream>>>(g2, cntf, out);
}

// Round 9
// 105.041 us; speedup vs baseline: 1.0272x; 1.0272x over previous
//
#include <hip/hip_runtime.h>
#include <math.h>

#define TOKENS 16384
#define HID    2048
#define KC     64
#define NCH    32
#define TPB    32          // tokens per block
#define TAU    0.02f

typedef float f4 __attribute__((ext_vector_type(4)));
typedef short s8v __attribute__((ext_vector_type(8)));

// ws byte layout
#define WS_W1    0                      // ushort[64*2048] bf16 weights (256KB)
#define WS_SLIST 262144                 // uint2[16384] suspect list (128KB)
#define WS_BP    393216                 // float[512*128] (256KB)
#define WS_G2    917504                 // float[64*128] (32KB)
#define WS_CNTF  950272                 // float[64]
#define WS_SCNT  950528                 // unsigned[1]

__device__ __forceinline__ unsigned short bf16rne(float x) {
  unsigned u = __float_as_uint(x);
  return (unsigned short)((u + 0x7FFFu + ((u >> 16) & 1u)) >> 16);
}

__device__ __forceinline__ void gl16(const void* g, const void* l) {
  __builtin_amdgcn_global_load_lds(
      (const __attribute__((address_space(1))) void*)g,
      (__attribute__((address_space(3))) void*)l, 16, 0, 0);
}

#define BARK(N) { asm volatile("s_waitcnt vmcnt(" #N ") lgkmcnt(0)" ::: "memory"); \
  __builtin_amdgcn_sched_barrier(0); __builtin_amdgcn_s_barrier(); \
  __builtin_amdgcn_sched_barrier(0); }

// fp32 weights -> bf16 (RNE); also zeroes fixup counters
__global__ __launch_bounds__(256) void k_pack(const float* __restrict__ gw,
                                              unsigned short* __restrict__ w1,
                                              float* __restrict__ cntf,
                                              unsigned* __restrict__ scnt) {
  if (blockIdx.x == 0) {
    if (threadIdx.x < 64) cntf[threadIdx.x] = 0.f;
    if (threadIdx.x == 64) *scnt = 0u;
  }
  int gid = blockIdx.x * 256 + threadIdx.x;
  int m = gid * 8;
  f4 a = *(const f4*)(gw + m);
  f4 b = *(const f4*)(gw + m + 4);
  unsigned short r[8] = {bf16rne(a.x), bf16rne(a.y), bf16rne(a.z), bf16rne(a.w),
                         bf16rne(b.x), bf16rne(b.y), bf16rne(b.z), bf16rne(b.w)};
  *(s8v*)(w1 + m) = *(s8v*)r;
}

__global__ __launch_bounds__(256, 2) void k_main(const float* __restrict__ hid,
                                                 const unsigned short* __restrict__ w1,
                                                 float* __restrict__ out,
                                                 float* __restrict__ bp,
                                                 uint2* __restrict__ slist,
                                                 unsigned* __restrict__ scnt) {
  // 3 buffers * 16384B: A fp32 [32 tok][256B] swizzled (8KB) + B bf16 [64 e][128B] swizzled (8KB)
  __shared__ __align__(16) char lds[49152];
  const int tid = threadIdx.x, wave = tid >> 6, lane = tid & 63;
  const int th = wave >> 1, eh = wave & 1;       // token-half, expert-half
  const int l15 = lane & 15, ks = lane >> 4;
  const int tok0 = blockIdx.x * TPB;

  // ---- staging sources (pre-swizzled granules; LDS dest linear) ----
  // A: instr j covers rows j*16+(tid>>4), 16B granule (tid&15) XOR row&15
  const char* hb = (const char*)hid;
  size_t asrc[2];
  #pragma unroll
  for (int j = 0; j < 2; ++j) {
    int row = j * 16 + (tid >> 4);
    asrc[j] = (size_t)(tok0 + row) * 8192 + (size_t)(((tid & 15) ^ (row & 15)) << 4);
  }
  // B: instr j covers experts j*32+(tid>>3), 16B granule (tid&7) XOR e&7
  const char* w1b = (const char*)w1;
  size_t bsrc[2];
  #pragma unroll
  for (int j = 0; j < 2; ++j) {
    int e = j * 32 + (tid >> 3);
    bsrc[j] = (size_t)e * 4096 + (size_t)(((tid & 7) ^ (e & 7)) << 4);
  }

  f4 acc[2] = {{0.f,0.f,0.f,0.f},{0.f,0.f,0.f,0.f}};
  const int arow = th * 16 + l15, asw = arow & 15;
  const int be[2] = {eh * 32 + l15, eh * 32 + 16 + l15};

  auto stage = [&](int c, int bufb) {
    #pragma unroll
    for (int j = 0; j < 2; ++j)
      gl16(hb + asrc[j] + (size_t)c * 256, lds + bufb + j * 4096 + wave * 1024);
    #pragma unroll
    for (int j = 0; j < 2; ++j)
      gl16(w1b + bsrc[j] + (size_t)c * 128, lds + bufb + 8192 + j * 4096 + wave * 1024);
  };

  auto compute = [&](int bufb) {
    #pragma unroll
    for (int s = 0; s < 2; ++s) {
      int g0 = (s * 8 + ks * 2) ^ asw;
      int g1 = (s * 8 + ks * 2 + 1) ^ asw;
      f4 a0 = *(const f4*)(lds + bufb + arow * 256 + g0 * 16);
      f4 a1 = *(const f4*)(lds + bufb + arow * 256 + g1 * 16);
      unsigned short af8[8] = {bf16rne(a0.x), bf16rne(a0.y), bf16rne(a0.z), bf16rne(a0.w),
                               bf16rne(a1.x), bf16rne(a1.y), bf16rne(a1.z), bf16rne(a1.w)};
      s8v af = *(s8v*)af8;
      #pragma unroll
      for (int nj = 0; nj < 2; ++nj) {
        int g = (s * 4 + ks) ^ (be[nj] & 7);
        s8v bf = *(const s8v*)(lds + bufb + 8192 + be[nj] * 128 + g * 16);
        acc[nj] = __builtin_amdgcn_mfma_f32_16x16x32_bf16(af, bf, acc[nj], 0, 0, 0);
      }
    }
  };

  stage(0, 0);
  stage(1, 16384);
  BARK(4);

  for (int c = 0; c < NCH; ++c) {
    const int bufb = (c % 3) * 16384;
    if (c + 2 < NCH) stage(c + 2, ((c + 2) % 3) * 16384);
    compute(bufb);
    if (c + 2 < NCH) { BARK(4); } else { BARK(0); }
  }

  // ---- epilogue: park logits [32 tok][68] fp32 ----
  float* lf = (float*)lds;
  #pragma unroll
  for (int nj = 0; nj < 2; ++nj)
    #pragma unroll
    for (int r = 0; r < 4; ++r)
      lf[(th * 16 + ks * 4 + r) * 68 + eh * 32 + nj * 16 + l15] = acc[nj][r];
  __syncthreads();

  float spacc = 0.f, cntacc = 0.f;
  for (int it = 0; it < 8; ++it) {
    const int tl = wave * 8 + it;
    float lg = lf[tl * 68 + lane];
    float m1 = lg;
    #pragma unroll
    for (int d = 1; d < 64; d <<= 1) m1 = fmaxf(m1, __shfl_xor(m1, d));
    int c0 = (lg == m1) ? lane : 64;
    #pragma unroll
    for (int d = 1; d < 64; d <<= 1) c0 = min(c0, __shfl_xor(c0, d));
    float lx1 = (lane == c0) ? -INFINITY : lg;
    float m2 = lx1;
    #pragma unroll
    for (int d = 1; d < 64; d <<= 1) m2 = fmaxf(m2, __shfl_xor(m2, d));
    int c1 = (lx1 == m2) ? lane : 64;
    #pragma unroll
    for (int d = 1; d < 64; d <<= 1) c1 = min(c1, __shfl_xor(c1, d));
    float lx2 = (lane == c0 || lane == c1) ? -INFINITY : lg;
    float m3 = lx2;
    #pragma unroll
    for (int d = 1; d < 64; d <<= 1) m3 = fmaxf(m3, __shfl_xor(m3, d));

    float p = __expf(lg - m1);
    float Z = p;
    #pragma unroll
    for (int d = 1; d < 64; d <<= 1) Z += __shfl_xor(Z, d);
    spacc = fmaf(p, 1.f / Z, spacc);

    const bool suspect = (m1 - m2 < TAU) || (m2 - m3 < TAU);
    if (!suspect) cntacc += ((lane == c0) ? 1.f : 0.f) + ((lane == c1) ? 1.f : 0.f);

    float gr = __expf(m2 - m1);
    float r0 = 1.f / (1.f + gr);
    if (lane == 0) {
      int t = tok0 + tl;
      out[(size_t)t * 2]     = r0;
      out[(size_t)t * 2 + 1] = gr * r0;
      out[(size_t)TOKENS * 2 + t * 2]     = (float)c0;
      out[(size_t)TOKENS * 2 + t * 2 + 1] = (float)c1;
    }
    if (suspect) {
      int c2 = (lx2 == m3) ? lane : 64;
      #pragma unroll
      for (int d = 1; d < 64; d <<= 1) c2 = min(c2, __shfl_xor(c2, d));
      float lx3 = (lane == c0 || lane == c1 || lane == c2) ? -INFINITY : lg;
      float m4 = lx3;
      #pragma unroll
      for (int d = 1; d < 64; d <<= 1) m4 = fmaxf(m4, __shfl_xor(m4, d));
      int c3 = (lx3 == m4) ? lane : 64;
      #pragma unroll
      for (int d = 1; d < 64; d <<= 1) c3 = min(c3, __shfl_xor(c3, d));
      if (lane == 0) {
        unsigned idx = atomicAdd(scnt, 1u);
        slist[idx] = make_uint2((unsigned)(tok0 + tl),
            (unsigned)c0 | ((unsigned)c1 << 8) | ((unsigned)c2 << 16) | ((unsigned)c3 << 24));
      }
    }
  }

  float* red = lf + 2304;
  red[wave * 128 + lane]      = spacc;
  red[wave * 128 + 64 + lane] = cntacc;
  __syncthreads();
  if (tid < 128) {
    float s = red[tid] + red[128 + tid] + red[256 + tid] + red[384 + tid];
    bp[(size_t)blockIdx.x * 128 + tid] = s;
  }
}

// exact fp32 re-rank of bf16 top-4 for suspect tokens
__global__ __launch_bounds__(256) void k_fixup(const float* __restrict__ hid,
                                               const float* __restrict__ gw,
                                               float* __restrict__ out,
                                               float* __restrict__ cntf,
                                               const uint2* __restrict__ slist,
                                               const unsigned* __restrict__ scnt) {
  const int lane = threadIdx.x & 63;
  const int wgid = blockIdx.x * 4 + (threadIdx.x >> 6);
  const unsigned S = *scnt;
  for (unsigned j = wgid; j < S; j += 1024) {
    uint2 rec = slist[j];
    const int tok = (int)rec.x;
    const float* hrow = hid + (size_t)tok * HID;
    f4 h[8];
    #pragma unroll
    for (int i = 0; i < 8; ++i) h[i] = *(const f4*)(hrow + lane * 4 + i * 256);
    float lgv[4]; int ide[4];
    #pragma unroll
    for (int c4 = 0; c4 < 4; ++c4) {
      int e = (int)((rec.y >> (8 * c4)) & 255u);
      const float* wr = gw + (size_t)e * HID;
      float s = 0.f;
      #pragma unroll
      for (int i = 0; i < 8; ++i) {
        f4 w = *(const f4*)(wr + lane * 4 + i * 256);
        s = fmaf(h[i].x, w.x, s); s = fmaf(h[i].y, w.y, s);
        s = fmaf(h[i].z, w.z, s); s = fmaf(h[i].w, w.w, s);
      }
      #pragma unroll
      for (int d = 1; d < 64; d <<= 1) s += __shfl_xor(s, d);
      lgv[c4] = s; ide[c4] = e;
    }
    #define SW(a,b) { bool sup = (lgv[b] > lgv[a]) || (lgv[b] == lgv[a] && ide[b] < ide[a]); \
      if (sup) { float tf = lgv[a]; lgv[a] = lgv[b]; lgv[b] = tf; \
                 int ti = ide[a]; ide[a] = ide[b]; ide[b] = ti; } }
    SW(0,1); SW(2,3); SW(0,2); SW(1,3); SW(1,2);
    #undef SW
    float gr = __expf(lgv[1] - lgv[0]);
    float r0 = 1.f / (1.f + gr);
    if (lane == 0) {
      out[(size_t)tok * 2]     = r0;
      out[(size_t)tok * 2 + 1] = gr * r0;
      out[(size_t)TOKENS * 2 + tok * 2]     = (float)ide[0];
      out[(size_t)TOKENS * 2 + tok * 2 + 1] = (float)ide[1];
      atomicAdd(&cntf[ide[0]], 1.f);
      atomicAdd(&cntf[ide[1]], 1.f);
    }
  }
}

__global__ __launch_bounds__(128) void k_loss1(const float* __restrict__ bp,
                                               float* __restrict__ g2) {
  float s = 0.f;
  #pragma unroll 4
  for (int j = 0; j < 8; ++j)
    s += bp[(size_t)(blockIdx.x * 8 + j) * 128 + threadIdx.x];
  g2[(size_t)blockIdx.x * 128 + threadIdx.x] = s;
}

__global__ __launch_bounds__(128) void k_loss2(const float* __restrict__ g2,
                                               const float* __restrict__ cntf,
                                               float* __restrict__ out) {
  const int tid = threadIdx.x;
  float s = 0.f;
  #pragma unroll 8
  for (int j = 0; j < 64; ++j) s += g2[(size_t)j * 128 + tid];
  __shared__ float red[128];
  red[tid] = s;
  __syncthreads();
  if (tid < 64) {
    float v = red[tid] * (red[64 + tid] + cntf[tid]);
    #pragma unroll
    for (int d = 1; d < 64; d <<= 1) v += __shfl_xor(v, d);
    if (tid == 0)
      out[(size_t)TOKENS * 4] = 0.01f * 64.f * v / (16384.f * 16384.f);
  }
}

extern "C" void kernel_launch(void* const* d_in, const int* in_sizes, int n_in,
                              void* d_out, int out_size, void* d_ws, size_t ws_size,
                              hipStream_t stream) {
  (void)in_sizes; (void)n_in; (void)out_size; (void)ws_size;
  const float* hid = (const float*)d_in[0];
  const float* gw  = (const float*)d_in[1];
  float* out = (float*)d_out;
  char* ws = (char*)d_ws;
  unsigned short* w1 = (unsigned short*)(ws + WS_W1);
  uint2* slist = (uint2*)(ws + WS_SLIST);
  float* bp    = (float*)(ws + WS_BP);
  float* g2    = (float*)(ws + WS_G2);
  float* cntf  = (float*)(ws + WS_CNTF);
  unsigned* scnt = (unsigned*)(ws + WS_SCNT);

  k_pack <<<64, 256, 0, stream>>>(gw, w1, cntf, scnt);
  k_main <<<512, 256, 0, stream>>>(hid, w1, out, bp, slist, scnt);
  k_fixup<<<256, 256, 0, stream>>>(hid, gw, out, cntf, slist, scnt);
  k_loss1<<<64, 128, 0, stream>>>(bp, g2);
  k_loss2<<<1, 128, 0, stream>>>(g2, cntf, out);
}

// Round 10
// 63.216 us; speedup vs baseline: 1.7069x; 1.6616x over previous
//
#include <hip/hip_runtime.h>
#include <math.h>

#define TOKENS 16384
#define HID    2048
#define KC     64
#define NCH    32
#define TPB    32          // tokens per block

typedef float f4 __attribute__((ext_vector_type(4)));
typedef short s8v __attribute__((ext_vector_type(8)));

// ws byte layout
#define WS_W1    0                      // ushort[64*2048] bf16 plane1 (256KB)
#define WS_W2    262144                 // ushort[64*2048] bf16 plane2 (256KB)
#define WS_BP    524288                 // float[512*128] (256KB)
#define WS_G2    786432                 // float[64*128] (32KB)

__device__ __forceinline__ unsigned short bf16rne(float x) {
  unsigned u = __float_as_uint(x);
  return (unsigned short)((u + 0x7FFFu + ((u >> 16) & 1u)) >> 16);
}

__device__ __forceinline__ void gl16(const void* g, const void* l) {
  __builtin_amdgcn_global_load_lds(
      (const __attribute__((address_space(1))) void*)g,
      (__attribute__((address_space(3))) void*)l, 16, 0, 0);
}

#define BARK(N) { asm volatile("s_waitcnt vmcnt(" #N ") lgkmcnt(0)" ::: "memory"); \
  __builtin_amdgcn_sched_barrier(0); __builtin_amdgcn_s_barrier(); \
  __builtin_amdgcn_sched_barrier(0); }

// fp32 weights -> two bf16 planes (w ~= w1 + w2, residual ~2^-18)
__global__ __launch_bounds__(256) void k_pack(const float* __restrict__ gw,
                                              unsigned short* __restrict__ w1,
                                              unsigned short* __restrict__ w2) {
  int gid = blockIdx.x * 256 + threadIdx.x;   // 16384 threads * 8 els
  int m = gid * 8;
  f4 a = *(const f4*)(gw + m);
  f4 b = *(const f4*)(gw + m + 4);
  float av[8] = {a.x, a.y, a.z, a.w, b.x, b.y, b.z, b.w};
  unsigned short p1[8], p2[8];
  #pragma unroll
  for (int i = 0; i < 8; ++i) {
    unsigned short h = bf16rne(av[i]);
    p1[i] = h;
    float r = av[i] - __uint_as_float((unsigned)h << 16);
    p2[i] = bf16rne(r);
  }
  *(s8v*)(w1 + m) = *(s8v*)p1;
  *(s8v*)(w2 + m) = *(s8v*)p2;
}

__global__ __launch_bounds__(256, 2) void k_main(const float* __restrict__ hid,
                                                 const unsigned short* __restrict__ w1,
                                                 const unsigned short* __restrict__ w2,
                                                 float* __restrict__ out,
                                                 float* __restrict__ bp) {
  // 3 buffers * 24576B: A fp32 [32 tok][256B] swz (8KB) + w1 [64 e][128B] swz (8KB) + w2 (8KB)
  __shared__ __align__(16) char lds[73728];
  const int tid = threadIdx.x, wave = tid >> 6, lane = tid & 63;
  const int th = wave >> 1, eh = wave & 1;       // token-half, expert-half
  const int l15 = lane & 15, ks = lane >> 4;
  const int tok0 = blockIdx.x * TPB;

  // ---- staging sources (pre-swizzled granules; LDS dest linear) ----
  const char* hb = (const char*)hid;
  size_t asrc[2];
  #pragma unroll
  for (int j = 0; j < 2; ++j) {
    int row = j * 16 + (tid >> 4);
    asrc[j] = (size_t)(tok0 + row) * 8192 + (size_t)(((tid & 15) ^ (row & 15)) << 4);
  }
  const char* w1b = (const char*)w1;
  const char* w2b = (const char*)w2;
  size_t bsrc[2];
  #pragma unroll
  for (int j = 0; j < 2; ++j) {
    int e = j * 32 + (tid >> 3);
    bsrc[j] = (size_t)e * 4096 + (size_t)(((tid & 7) ^ (e & 7)) << 4);
  }

  f4 acc[2] = {{0.f,0.f,0.f,0.f},{0.f,0.f,0.f,0.f}};
  const int arow = th * 16 + l15, asw = arow & 15;
  const int be[2] = {eh * 32 + l15, eh * 32 + 16 + l15};

  auto stage = [&](int c, int bufb) {
    #pragma unroll
    for (int j = 0; j < 2; ++j)
      gl16(hb + asrc[j] + (size_t)c * 256, lds + bufb + j * 4096 + wave * 1024);
    #pragma unroll
    for (int j = 0; j < 2; ++j)
      gl16(w1b + bsrc[j] + (size_t)c * 128, lds + bufb + 8192 + j * 4096 + wave * 1024);
    #pragma unroll
    for (int j = 0; j < 2; ++j)
      gl16(w2b + bsrc[j] + (size_t)c * 128, lds + bufb + 16384 + j * 4096 + wave * 1024);
  };

  auto compute = [&](int bufb) {
    #pragma unroll
    for (int s = 0; s < 2; ++s) {
      int g0 = (s * 8 + ks * 2) ^ asw;
      int g1 = (s * 8 + ks * 2 + 1) ^ asw;
      f4 a0 = *(const f4*)(lds + bufb + arow * 256 + g0 * 16);
      f4 a1 = *(const f4*)(lds + bufb + arow * 256 + g1 * 16);
      float av[8] = {a0.x, a0.y, a0.z, a0.w, a1.x, a1.y, a1.z, a1.w};
      unsigned short p1[8], p2[8];
      #pragma unroll
      for (int i = 0; i < 8; ++i) {
        unsigned short h = bf16rne(av[i]);
        p1[i] = h;
        float r = av[i] - __uint_as_float((unsigned)h << 16);
        p2[i] = bf16rne(r);
      }
      s8v af1 = *(s8v*)p1;
      s8v af2 = *(s8v*)p2;
      #pragma unroll
      for (int nj = 0; nj < 2; ++nj) {
        int g = (s * 4 + ks) ^ (be[nj] & 7);
        s8v bw1 = *(const s8v*)(lds + bufb + 8192  + be[nj] * 128 + g * 16);
        s8v bw2 = *(const s8v*)(lds + bufb + 16384 + be[nj] * 128 + g * 16);
        acc[nj] = __builtin_amdgcn_mfma_f32_16x16x32_bf16(af1, bw1, acc[nj], 0, 0, 0);
        acc[nj] = __builtin_amdgcn_mfma_f32_16x16x32_bf16(af1, bw2, acc[nj], 0, 0, 0);
        acc[nj] = __builtin_amdgcn_mfma_f32_16x16x32_bf16(af2, bw1, acc[nj], 0, 0, 0);
      }
    }
  };

  stage(0, 0);
  stage(1, 24576);
  BARK(6);

  for (int c = 0; c < NCH; ++c) {
    const int bufb = (c % 3) * 24576;
    if (c + 2 < NCH) stage(c + 2, ((c + 2) % 3) * 24576);
    compute(bufb);
    if (c + 2 < NCH) { BARK(6); } else { BARK(0); }
  }

  // ---- epilogue: park logits [32 tok][68] fp32 ----
  float* lf = (float*)lds;
  #pragma unroll
  for (int nj = 0; nj < 2; ++nj)
    #pragma unroll
    for (int r = 0; r < 4; ++r)
      lf[(th * 16 + ks * 4 + r) * 68 + eh * 32 + nj * 16 + l15] = acc[nj][r];
  __syncthreads();

  float spacc = 0.f, cntacc = 0.f;
  for (int it = 0; it < 8; ++it) {
    const int tl = wave * 8 + it;
    float lg = lf[tl * 68 + lane];
    float m1 = lg;
    #pragma unroll
    for (int d = 1; d < 64; d <<= 1) m1 = fmaxf(m1, __shfl_xor(m1, d));
    int c0 = (lg == m1) ? lane : 64;
    #pragma unroll
    for (int d = 1; d < 64; d <<= 1) c0 = min(c0, __shfl_xor(c0, d));
    float lx1 = (lane == c0) ? -INFINITY : lg;
    float m2 = lx1;
    #pragma unroll
    for (int d = 1; d < 64; d <<= 1) m2 = fmaxf(m2, __shfl_xor(m2, d));
    int c1 = (lx1 == m2) ? lane : 64;
    #pragma unroll
    for (int d = 1; d < 64; d <<= 1) c1 = min(c1, __shfl_xor(c1, d));

    float p = __expf(lg - m1);
    float Z = p;
    #pragma unroll
    for (int d = 1; d < 64; d <<= 1) Z += __shfl_xor(Z, d);
    spacc = fmaf(p, 1.f / Z, spacc);
    cntacc += ((lane == c0) ? 1.f : 0.f) + ((lane == c1) ? 1.f : 0.f);

    float gr = __expf(m2 - m1);
    float r0 = 1.f / (1.f + gr);
    if (lane == 0) {
      int t = tok0 + tl;
      out[(size_t)t * 2]     = r0;
      out[(size_t)t * 2 + 1] = gr * r0;
      out[(size_t)TOKENS * 2 + t * 2]     = (float)c0;
      out[(size_t)TOKENS * 2 + t * 2 + 1] = (float)c1;
    }
  }

  float* red = lf + 2304;
  red[wave * 128 + lane]      = spacc;
  red[wave * 128 + 64 + lane] = cntacc;
  __syncthreads();
  if (tid < 128) {
    float s = red[tid] + red[128 + tid] + red[256 + tid] + red[384 + tid];
    bp[(size_t)blockIdx.x * 128 + tid] = s;
  }
}

__global__ __launch_bounds__(128) void k_loss1(const float* __restrict__ bp,
                                               float* __restrict__ g2) {
  float s = 0.f;
  #pragma unroll 4
  for (int j = 0; j < 8; ++j)
    s += bp[(size_t)(blockIdx.x * 8 + j) * 128 + threadIdx.x];
  g2[(size_t)blockIdx.x * 128 + threadIdx.x] = s;
}

__global__ __launch_bounds__(128) void k_loss2(const float* __restrict__ g2,
                                               float* __restrict__ out) {
  const int tid = threadIdx.x;
  float s = 0.f;
  #pragma unroll 8
  for (int j = 0; j < 64; ++j) s += g2[(size_t)j * 128 + tid];
  __shared__ float red[128];
  red[tid] = s;
  __syncthreads();
  if (tid < 64) {
    float v = red[tid] * red[64 + tid];   // sumprob_e * count_e
    #pragma unroll
    for (int d = 1; d < 64; d <<= 1) v += __shfl_xor(v, d);
    if (tid == 0)
      out[(size_t)TOKENS * 4] = 0.01f * 64.f * v / (16384.f * 16384.f);
  }
}

extern "C" void kernel_launch(void* const* d_in, const int* in_sizes, int n_in,
                              void* d_out, int out_size, void* d_ws, size_t ws_size,
                              hipStream_t stream) {
  (void)in_sizes; (void)n_in; (void)out_size; (void)ws_size;
  const float* hid = (const float*)d_in[0];
  const float* gw  = (const float*)d_in[1];
  float* out = (float*)d_out;
  char* ws = (char*)d_ws;
  unsigned short* w1 = (unsigned short*)(ws + WS_W1);
  unsigned short* w2 = (unsigned short*)(ws + WS_W2);
  float* bp    = (float*)(ws + WS_BP);
  float* g2    = (float*)(ws + WS_G2);

  k_pack <<<64, 256, 0, stream>>>(gw, w1, w2);
  k_main <<<512, 256, 0, stream>>>(hid, w1, w2, out, bp);
  k_loss1<<<64, 128, 0, stream>>>(bp, g2);
  k_loss2<<<1, 128, 0, stream>>>(g2, out);
}